// Round 4
// baseline (304.300 us; speedup 1.0000x reference)
//
#include <hip/hip_runtime.h>
#include <math.h>

#define N_NODES 60000
#define N_EDGES 240000
#define F_INQ 10
#define G_DIM 512
#define NB_SCAN ((N_NODES + 255) / 256)   // 235
#define NB_EDGE ((N_EDGES + 255) / 256)   // 938

// ===========================================================================
// CSR build. rs = per-node degree -> per-block exclusive scan (k_scan_a) with
// block sums exclusive-scanned in k_scan_b. k_fill computes global slots as
// local_scan + bsum[block] (scan_c folded away) and writes REORDERED edge
// records: ecol[slot] = col, edata[slot] = (a, e0, e1, e2). After k_fill,
// rs[i] = block-local inclusive end; global end = rs[i] + bsum[i>>8].
// ===========================================================================
__global__ __launch_bounds__(256) void k_deg(
    const int* __restrict__ ei, int* __restrict__ rs)
{
    int e = blockIdx.x * 256 + threadIdx.x;
    if (e < N_EDGES) atomicAdd(&rs[ei[e]], 1);
}

__global__ __launch_bounds__(256) void k_scan_a(
    int* __restrict__ rs, int* __restrict__ bsum)
{
    __shared__ int s[256];
    int i = blockIdx.x * 256 + threadIdx.x;
    int v = (i < N_NODES) ? rs[i] : 0;
    s[threadIdx.x] = v;
    __syncthreads();
    for (int off = 1; off < 256; off <<= 1) {
        int t = (threadIdx.x >= off) ? s[threadIdx.x - off] : 0;
        __syncthreads();
        s[threadIdx.x] += t;
        __syncthreads();
    }
    if (i < N_NODES) rs[i] = s[threadIdx.x] - v;  // block-local exclusive
    if (threadIdx.x == 255) bsum[blockIdx.x] = s[255];
}

__global__ __launch_bounds__(256) void k_scan_b(int* __restrict__ bsum)
{
    __shared__ int s[256];
    int v = (threadIdx.x < NB_SCAN) ? bsum[threadIdx.x] : 0;
    s[threadIdx.x] = v;
    __syncthreads();
    for (int off = 1; off < 256; off <<= 1) {
        int t = (threadIdx.x >= off) ? s[threadIdx.x - off] : 0;
        __syncthreads();
        s[threadIdx.x] += t;
        __syncthreads();
    }
    if (threadIdx.x < NB_SCAN) bsum[threadIdx.x] = s[threadIdx.x] - v;  // exclusive
}

__global__ __launch_bounds__(256) void k_fill(
    const int* __restrict__ ei, const float* __restrict__ a_vals,
    const float* __restrict__ efeat,
    int* __restrict__ rs, const int* __restrict__ bsum,
    int* __restrict__ ecol, float4* __restrict__ edata)
{
    int e = blockIdx.x * 256 + threadIdx.x;
    if (e >= N_EDGES) return;
    int row = ei[e];
    int slot = atomicAdd(&rs[row], 1) + bsum[row >> 8];
    ecol[slot] = ei[N_EDGES + e];
    edata[slot] = make_float4(a_vals[e], efeat[e * 3], efeat[e * 3 + 1], efeat[e * 3 + 2]);
}

// gs[g] = first node of graph g (seg is sorted); gs[G] = N.
__global__ __launch_bounds__(256) void k_gseg(
    const int* __restrict__ seg, int* __restrict__ gs)
{
    int i = blockIdx.x * 256 + threadIdx.x;
    if (i >= N_NODES) return;
    int s = seg[i];
    if (i == 0) { for (int g = 0; g <= s; ++g) gs[g] = 0; }
    else {
        int pr = seg[i - 1];
        for (int g = pr + 1; g <= s; ++g) gs[g] = i;
    }
    if (i == N_NODES - 1) { for (int g = s + 1; g <= G_DIM; ++g) gs[g] = N_NODES; }
}

// ---------------------------------------------------------------------------
// K_gather1: layer 1, recompute-at-gather. Thread (node, o<16). Per edge reads
// 40B x-row + 20B edge record; per-f: wc = bm + e0*w0 + e1*w1 + e2*w2;
// c += x_f*wc; gx += x_f*wg. Weights hoisted LDS->registers (50 VGPRs).
// Epilogue fuses root1/bias1/b_gcn1 + relu.  k1/A array eliminated.
// ---------------------------------------------------------------------------
__global__ __launch_bounds__(256) void k_gather1(
    const float* __restrict__ x,
    const int* __restrict__ rs, const int* __restrict__ bsum,
    const int* __restrict__ ecol, const float4* __restrict__ edata,
    const float* __restrict__ Wg1,   // [10,16]
    const float* __restrict__ We1,   // [3,160]
    const float* __restrict__ be1,   // [160]
    const float* __restrict__ root1, // [160]
    const float* __restrict__ bias1, // [16]
    const float* __restrict__ bg1,   // [16]
    float* __restrict__ g1, float* __restrict__ c1)
{
    // LDS: wg1|w0|w1|w2|bm|root1 (160 each) | bias1(16) | bg1(16)
    __shared__ float w[6 * 160 + 32];
    for (int t = threadIdx.x; t < 6 * 160 + 32; t += 256) {
        float v;
        if (t < 960) {
            int slot = t / 160, r = t - slot * 160;
            if (slot == 0)      v = Wg1[r];
            else if (slot <= 3) v = We1[(slot - 1) * 160 + r];
            else if (slot == 4) v = be1[r];
            else                v = root1[r];
        } else if (t < 976) v = bias1[t - 960];
        else                v = bg1[t - 976];
        w[t] = v;
    }
    __syncthreads();

    int idx = blockIdx.x * 256 + threadIdx.x;   // exact: 3750*256 = N*16
    int node = idx >> 4, o = idx & 15;

    float wg[10], w0[10], w1[10], w2[10], bm[10];
#pragma unroll
    for (int f = 0; f < 10; ++f) {
        wg[f] = w[f * 16 + o];
        w0[f] = w[160 + f * 16 + o];
        w1[f] = w[320 + f * 16 + o];
        w2[f] = w[480 + f * 16 + o];
        bm[f] = w[640 + f * 16 + o];
    }

    int end = rs[node] + bsum[node >> 8];
    int start = (node == 0) ? 0 : (rs[node - 1] + bsum[(node - 1) >> 8]);

    float g = 0.f, c = 0.f;
    for (int k = start; k < end; ++k) {
        int col = ecol[k];
        float4 ed = edata[k];
        const float2* xp = reinterpret_cast<const float2*>(x + col * F_INQ);
        float2 xa = xp[0], xb = xp[1], xc = xp[2], xd = xp[3], xe = xp[4];
        float xs[10] = {xa.x, xa.y, xb.x, xb.y, xc.x, xc.y, xd.x, xd.y, xe.x, xe.y};
        float gx = 0.f, cx = 0.f;
#pragma unroll
        for (int f = 0; f < 10; ++f) {
            float wc = bm[f] + ed.y * w0[f] + ed.z * w1[f] + ed.w * w2[f];
            cx += xs[f] * wc;
            gx += xs[f] * wg[f];
        }
        g += ed.x * gx;
        c += cx;
    }

    // epilogue: self terms
    const float2* xp = reinterpret_cast<const float2*>(x + node * F_INQ);
    float2 xa = xp[0], xb = xp[1], xc = xp[2], xd = xp[3], xe = xp[4];
    float xs[10] = {xa.x, xa.y, xb.x, xb.y, xc.x, xc.y, xd.x, xd.y, xe.x, xe.y};
    float rt = 0.f;
#pragma unroll
    for (int f = 0; f < 10; ++f) rt += xs[f] * w[800 + f * 16 + o];
    float cv = c + rt + w[960 + o];
    float gv = g + w[976 + o];
    g1[node * 16 + o] = gv > 0.f ? gv : 0.f;
    c1[node * 16 + o] = cv > 0.f ? cv : 0.f;
}

// ---------------------------------------------------------------------------
// K_gather2: layer 2, recompute-at-gather. Thread (node, o<32). Per edge reads
// g1-row 64B + c1-row 64B (both L2-resident, 3.8 MB each) + 20B edge record.
// 80 FMA/edge-lane. k4b/B array eliminated.
// ---------------------------------------------------------------------------
__global__ __launch_bounds__(256) void k_gather2(
    const float* __restrict__ g1, const float* __restrict__ c1,
    const int* __restrict__ rs, const int* __restrict__ bsum,
    const int* __restrict__ ecol, const float4* __restrict__ edata,
    const float* __restrict__ Wg2,   // [16,32]
    const float* __restrict__ We2,   // [3,512]
    const float* __restrict__ be2,   // [512]
    const float* __restrict__ root2, // [512]
    const float* __restrict__ bias2, // [32]
    const float* __restrict__ bg2,   // [32]
    float* __restrict__ g2, float* __restrict__ c2)
{
    // LDS: wg2|w0|w1|w2|bm|root2 (512 each) | bias2(32) | bg2(32)
    __shared__ float w[6 * 512 + 64];
    for (int t = threadIdx.x; t < 6 * 512 + 64; t += 256) {
        float v;
        if (t < 3072) {
            int slot = t >> 9, r = t & 511;
            if (slot == 0)      v = Wg2[r];
            else if (slot <= 3) v = We2[(slot - 1) * 512 + r];
            else if (slot == 4) v = be2[r];
            else                v = root2[r];
        } else if (t < 3104) v = bias2[t - 3072];
        else                 v = bg2[t - 3104];
        w[t] = v;
    }
    __syncthreads();

    int idx = blockIdx.x * 256 + threadIdx.x;   // exact: 7500*256 = N*32
    int node = idx >> 5, o = idx & 31;

    float wg[16], w0[16], w1[16], w2[16], bm[16];
#pragma unroll
    for (int f = 0; f < 16; ++f) {
        wg[f] = w[f * 32 + o];
        w0[f] = w[512 + f * 32 + o];
        w1[f] = w[1024 + f * 32 + o];
        w2[f] = w[1536 + f * 32 + o];
        bm[f] = w[2048 + f * 32 + o];
    }

    int end = rs[node] + bsum[node >> 8];
    int start = (node == 0) ? 0 : (rs[node - 1] + bsum[(node - 1) >> 8]);

    float g = 0.f, c = 0.f;
    for (int k = start; k < end; ++k) {
        int col = ecol[k];
        float4 ed = edata[k];
        const float4* gp = reinterpret_cast<const float4*>(g1 + col * 16);
        const float4* cp = reinterpret_cast<const float4*>(c1 + col * 16);
        float4 ga = gp[0], gb = gp[1], gc = gp[2], gd = gp[3];
        float4 ca = cp[0], cb = cp[1], cc = cp[2], cd = cp[3];
        float gr[16] = {ga.x, ga.y, ga.z, ga.w, gb.x, gb.y, gb.z, gb.w,
                        gc.x, gc.y, gc.z, gc.w, gd.x, gd.y, gd.z, gd.w};
        float cr[16] = {ca.x, ca.y, ca.z, ca.w, cb.x, cb.y, cb.z, cb.w,
                        cc.x, cc.y, cc.z, cc.w, cd.x, cd.y, cd.z, cd.w};
        float gx = 0.f, cx = 0.f;
#pragma unroll
        for (int f = 0; f < 16; ++f) {
            float wc = bm[f] + ed.y * w0[f] + ed.z * w1[f] + ed.w * w2[f];
            cx += cr[f] * wc;
            gx += gr[f] * wg[f];
        }
        g += ed.x * gx;
        c += cx;
    }

    // epilogue: self terms (root2 from LDS, c1 self row)
    const float4* cp = reinterpret_cast<const float4*>(c1 + node * 16);
    float4 ca = cp[0], cb = cp[1], cc = cp[2], cd = cp[3];
    float cr[16] = {ca.x, ca.y, ca.z, ca.w, cb.x, cb.y, cb.z, cb.w,
                    cc.x, cc.y, cc.z, cc.w, cd.x, cd.y, cd.z, cd.w};
    float rt = 0.f;
#pragma unroll
    for (int f = 0; f < 16; ++f) rt += cr[f] * w[2560 + f * 32 + o];
    float cv = c + rt + w[3072 + o];
    float gv = g + w[3104 + o];
    g2[node * 32 + o] = gv > 0.f ? gv : 0.f;
    c2[node * 32 + o] = cv > 0.f ? cv : 0.f;
}

// ---------------------------------------------------------------------------
// K_pool_head: one block per graph (512 blocks). 4 waves stride the graph's
// node range (lane = channel j<64), LDS-reduce, then fused MLP head.
// No atomics, no p array, no memset.
// ---------------------------------------------------------------------------
__global__ __launch_bounds__(256) void k_pool_head(
    const float* __restrict__ g2, const float* __restrict__ c2,
    const int* __restrict__ gs,
    const float* __restrict__ Wd1, const float* __restrict__ bd1,
    const float* __restrict__ Wd2, const float* __restrict__ bd2,
    const float* __restrict__ Wo,  const float* __restrict__ bo,
    float* __restrict__ out)
{
    __shared__ float red[4][64];
    __shared__ float pl[64];
    __shared__ float h1s[16], h2s[8];
    int g = blockIdx.x;
    int s = gs[g], e = gs[g + 1];
    int wv = threadIdx.x >> 6, j = threadIdx.x & 63;
    float acc = 0.f;
    for (int n = s + wv; n < e; n += 4)
        acc += (j < 32) ? g2[n * 32 + j] : c2[n * 32 + (j - 32)];
    red[wv][j] = acc;
    __syncthreads();
    if (wv == 0) pl[j] = red[0][j] + red[1][j] + red[2][j] + red[3][j];
    __syncthreads();
    int t = threadIdx.x;
    if (t < 16) {
        float a = bd1[t];
        for (int k = 0; k < 64; ++k) a += pl[k] * Wd1[k * 16 + t];
        h1s[t] = a > 0.f ? a : 0.f;
    }
    __syncthreads();
    if (t < 8) {
        float a = bd2[t];
        for (int k = 0; k < 16; ++k) a += h1s[k] * Wd2[k * 8 + t];
        h2s[t] = a > 0.f ? a : 0.f;
    }
    __syncthreads();
    if (t == 0) {
        float a = bo[0];
        for (int k = 0; k < 8; ++k) a += h2s[k] * Wo[k];
        out[g] = 1.f / (1.f + expf(-a));
    }
}

// ---------------------------------------------------------------------------
// Workspace layout (~28 MB):
//   edata [E]float4 | g1 N*16 | c1 N*16 | g2 N*32 | c2 N*32 (floats)
//   rs[N] | bsum[256] | gs[G+1] | ecol[E] (ints)
// ---------------------------------------------------------------------------
extern "C" void kernel_launch(void* const* d_in, const int* in_sizes, int n_in,
                              void* d_out, int out_size, void* d_ws, size_t ws_size,
                              hipStream_t stream)
{
    const float* x      = (const float*)d_in[0];
    const float* a_vals = (const float*)d_in[1];
    const float* efeat  = (const float*)d_in[2];
    const int*   ei     = (const int*)d_in[3];
    const int*   seg    = (const int*)d_in[4];
    const float* Wg1    = (const float*)d_in[5];
    const float* bg1    = (const float*)d_in[6];
    const float* Wg2    = (const float*)d_in[7];
    const float* bg2    = (const float*)d_in[8];
    const float* We1    = (const float*)d_in[9];
    const float* be1    = (const float*)d_in[10];
    const float* root1  = (const float*)d_in[11];
    const float* bias1  = (const float*)d_in[12];
    const float* We2    = (const float*)d_in[13];
    const float* be2    = (const float*)d_in[14];
    const float* root2  = (const float*)d_in[15];
    const float* bias2  = (const float*)d_in[16];
    const float* Wd1    = (const float*)d_in[17];
    const float* bd1    = (const float*)d_in[18];
    const float* Wd2    = (const float*)d_in[19];
    const float* bd2    = (const float*)d_in[20];
    const float* Wo     = (const float*)d_in[21];
    const float* bo     = (const float*)d_in[22];

    float4* edata = (float4*)d_ws;
    float*  g1   = (float*)(edata + N_EDGES);
    float*  c1   = g1 + (size_t)N_NODES * 16;
    float*  g2   = c1 + (size_t)N_NODES * 16;
    float*  c2   = g2 + (size_t)N_NODES * 32;
    int*    rs   = (int*)(c2 + (size_t)N_NODES * 32);
    int*    bsum = rs + N_NODES;
    int*    gs   = bsum + 256;
    int*    ecol = gs + (G_DIM + 1);
    float*  out  = (float*)d_out;

    hipMemsetAsync(rs, 0, sizeof(int) * N_NODES, stream);

    k_deg    <<<NB_EDGE, 256, 0, stream>>>(ei, rs);
    k_scan_a <<<NB_SCAN, 256, 0, stream>>>(rs, bsum);
    k_scan_b <<<1, 256, 0, stream>>>(bsum);
    k_fill   <<<NB_EDGE, 256, 0, stream>>>(ei, a_vals, efeat, rs, bsum, ecol, edata);
    k_gseg   <<<NB_SCAN, 256, 0, stream>>>(seg, gs);

    k_gather1<<<N_NODES * 16 / 256, 256, 0, stream>>>(
        x, rs, bsum, ecol, edata, Wg1, We1, be1, root1, bias1, bg1, g1, c1);
    k_gather2<<<N_NODES * 32 / 256, 256, 0, stream>>>(
        g1, c1, rs, bsum, ecol, edata, Wg2, We2, be2, root2, bias2, bg2, g2, c2);
    k_pool_head<<<G_DIM, 256, 0, stream>>>(
        g2, c2, gs, Wd1, bd1, Wd2, bd2, Wo, bo, out);
}

// Round 5
// 225.136 us; speedup vs baseline: 1.3516x; 1.3516x over previous
//
#include <hip/hip_runtime.h>
#include <math.h>

#define N_NODES 60000
#define N_EDGES 240000
#define F_INQ 10
#define G_DIM 512
#define NB_SCAN ((N_NODES + 255) / 256)   // 235
#define NB_EDGE ((N_EDGES + 255) / 256)   // 938

// ===========================================================================
// CSR build (unchanged from R4): deg -> block scan -> block-sum scan -> fill
// with reordered edge records. After k_fill: global end(i) = rs[i]+bsum[i>>8].
// ===========================================================================
__global__ __launch_bounds__(256) void k_deg(
    const int* __restrict__ ei, int* __restrict__ rs)
{
    int e = blockIdx.x * 256 + threadIdx.x;
    if (e < N_EDGES) atomicAdd(&rs[ei[e]], 1);
}

__global__ __launch_bounds__(256) void k_scan_a(
    int* __restrict__ rs, int* __restrict__ bsum)
{
    __shared__ int s[256];
    int i = blockIdx.x * 256 + threadIdx.x;
    int v = (i < N_NODES) ? rs[i] : 0;
    s[threadIdx.x] = v;
    __syncthreads();
    for (int off = 1; off < 256; off <<= 1) {
        int t = (threadIdx.x >= off) ? s[threadIdx.x - off] : 0;
        __syncthreads();
        s[threadIdx.x] += t;
        __syncthreads();
    }
    if (i < N_NODES) rs[i] = s[threadIdx.x] - v;  // block-local exclusive
    if (threadIdx.x == 255) bsum[blockIdx.x] = s[255];
}

__global__ __launch_bounds__(256) void k_scan_b(int* __restrict__ bsum)
{
    __shared__ int s[256];
    int v = (threadIdx.x < NB_SCAN) ? bsum[threadIdx.x] : 0;
    s[threadIdx.x] = v;
    __syncthreads();
    for (int off = 1; off < 256; off <<= 1) {
        int t = (threadIdx.x >= off) ? s[threadIdx.x - off] : 0;
        __syncthreads();
        s[threadIdx.x] += t;
        __syncthreads();
    }
    if (threadIdx.x < NB_SCAN) bsum[threadIdx.x] = s[threadIdx.x] - v;  // exclusive
}

__global__ __launch_bounds__(256) void k_fill(
    const int* __restrict__ ei, const float* __restrict__ a_vals,
    const float* __restrict__ efeat,
    int* __restrict__ rs, const int* __restrict__ bsum,
    int* __restrict__ ecol, float4* __restrict__ edata)
{
    int e = blockIdx.x * 256 + threadIdx.x;
    if (e >= N_EDGES) return;
    int row = ei[e];
    int slot = atomicAdd(&rs[row], 1) + bsum[row >> 8];
    ecol[slot] = ei[N_EDGES + e];
    edata[slot] = make_float4(a_vals[e], efeat[e * 3], efeat[e * 3 + 1], efeat[e * 3 + 2]);
}

// gs[g] = first node of graph g (seg sorted); gs[G] = N.
__global__ __launch_bounds__(256) void k_gseg(
    const int* __restrict__ seg, int* __restrict__ gs)
{
    int i = blockIdx.x * 256 + threadIdx.x;
    if (i >= N_NODES) return;
    int s = seg[i];
    if (i == 0) { for (int g = 0; g <= s; ++g) gs[g] = 0; }
    else {
        int pr = seg[i - 1];
        for (int g = pr + 1; g <= s; ++g) gs[g] = i;
    }
    if (i == N_NODES - 1) { for (int g = s + 1; g <= G_DIM; ++g) gs[g] = N_NODES; }
}

// ---------------------------------------------------------------------------
// K_edge1: weight-free CSR reduction, layer 1. Lane = (node, f<10) (16-lane
// groups, lanes 10-15 idle). Per edge: xv = x[col*10+f] (coalesced 40B),
// ed broadcast; 5 accumulators. PQ1[n,50] = [P0|P1|P2|P3|Q] (10 each).
//   P0 = sum x[col,f]; Ps = sum e_s*x[col,f]; Q = sum a*x[col,f].
// ---------------------------------------------------------------------------
__global__ __launch_bounds__(256) void k_edge1(
    const float* __restrict__ x,
    const int* __restrict__ rs, const int* __restrict__ bsum,
    const int* __restrict__ ecol, const float4* __restrict__ edata,
    float* __restrict__ PQ1)
{
    int idx = blockIdx.x * 256 + threadIdx.x;   // 3750 blocks exact
    int node = idx >> 4, f = idx & 15;
    if (f >= F_INQ) return;
    int end = rs[node] + bsum[node >> 8];
    int start = (node == 0) ? 0 : (rs[node - 1] + bsum[(node - 1) >> 8]);
    float p0 = 0.f, p1 = 0.f, p2 = 0.f, p3 = 0.f, q = 0.f;
    for (int k = start; k < end; ++k) {
        int col = ecol[k];
        float4 ed = edata[k];
        float xv = x[col * F_INQ + f];
        p0 += xv;
        p1 += ed.y * xv;
        p2 += ed.z * xv;
        p3 += ed.w * xv;
        q  += ed.x * xv;
    }
    float* P = PQ1 + node * 50;
    P[f]      = p0;
    P[10 + f] = p1;
    P[20 + f] = p2;
    P[30 + f] = p3;
    P[40 + f] = q;
}

// ---------------------------------------------------------------------------
// K_tf1: per-node transform 1. Thread = (node, o<16), o FIXED per thread so
// 60 weight floats live in VGPRs; grid-stride over nodes (16 nodes/block/iter).
//   c1 = relu(P0@be1 + sum_s Ps@We1_s + x_self@root1 + bias1)
//   g1 = relu(Q@Wg1 + b_gcn1)
// Output interleaved g1c1[n,32] = [g1(16)|c1(16)].
// ---------------------------------------------------------------------------
__global__ __launch_bounds__(256, 4) void k_tf1(
    const float* __restrict__ PQ1,
    const float* __restrict__ x,
    const float* __restrict__ Wg1,   // [10,16]
    const float* __restrict__ We1,   // [3,160]
    const float* __restrict__ be1,   // [160]
    const float* __restrict__ root1, // [10,16]
    const float* __restrict__ bias1, // [16]
    const float* __restrict__ bg1,   // [16]
    float* __restrict__ g1c1)
{
    // LDS: wg(160)|w0|w1|w2|bm|rt (160 each) | bias1(16) | bg1(16)
    __shared__ float w[6 * 160 + 32];
    for (int t = threadIdx.x; t < 6 * 160 + 32; t += 256) {
        float v;
        if (t < 960) {
            int slot = t / 160, r = t - slot * 160;
            if (slot == 0)      v = Wg1[r];
            else if (slot <= 3) v = We1[(slot - 1) * 160 + r];
            else if (slot == 4) v = be1[r];
            else                v = root1[r];
        } else if (t < 976) v = bias1[t - 960];
        else                v = bg1[t - 976];
        w[t] = v;
    }
    __syncthreads();
    int o = threadIdx.x & 15;
    int ngrp = threadIdx.x >> 4;         // 0..15
    float wg[10], w0[10], w1[10], w2[10], bm[10], rt[10];
#pragma unroll
    for (int f = 0; f < 10; ++f) {
        wg[f] = w[f * 16 + o];
        w0[f] = w[160 + f * 16 + o];
        w1[f] = w[320 + f * 16 + o];
        w2[f] = w[480 + f * 16 + o];
        bm[f] = w[640 + f * 16 + o];
        rt[f] = w[800 + f * 16 + o];
    }
    float bia = w[960 + o], bgv = w[976 + o];
    for (int node = blockIdx.x * 16 + ngrp; node < N_NODES; node += gridDim.x * 16) {
        const float* P = PQ1 + node * 50;
        const float* xs = x + node * F_INQ;
        float ac = bia, ag = bgv;
#pragma unroll
        for (int f = 0; f < 10; ++f) {
            ac += P[f] * bm[f] + P[10 + f] * w0[f] + P[20 + f] * w1[f]
                + P[30 + f] * w2[f] + xs[f] * rt[f];
            ag += P[40 + f] * wg[f];
        }
        g1c1[node * 32 + o]      = ag > 0.f ? ag : 0.f;
        g1c1[node * 32 + 16 + o] = ac > 0.f ? ac : 0.f;
    }
}

// ---------------------------------------------------------------------------
// K_edge2: weight-free CSR reduction, layer 2. Lane = (node, f<16). Per edge:
// gv = g1c1[col*32+f], cv = g1c1[col*32+16+f] (two coalesced 64B loads).
// PQ2[n,80] = [P0|P1|P2|P3|Q] (16 each); P* over c1, Q over a*g1.
// ---------------------------------------------------------------------------
__global__ __launch_bounds__(256) void k_edge2(
    const float* __restrict__ g1c1,
    const int* __restrict__ rs, const int* __restrict__ bsum,
    const int* __restrict__ ecol, const float4* __restrict__ edata,
    float* __restrict__ PQ2)
{
    int idx = blockIdx.x * 256 + threadIdx.x;   // 3750 blocks exact
    int node = idx >> 4, f = idx & 15;
    int end = rs[node] + bsum[node >> 8];
    int start = (node == 0) ? 0 : (rs[node - 1] + bsum[(node - 1) >> 8]);
    float p0 = 0.f, p1 = 0.f, p2 = 0.f, p3 = 0.f, q = 0.f;
    for (int k = start; k < end; ++k) {
        int col = ecol[k];
        float4 ed = edata[k];
        float gv = g1c1[col * 32 + f];
        float cv = g1c1[col * 32 + 16 + f];
        p0 += cv;
        p1 += ed.y * cv;
        p2 += ed.z * cv;
        p3 += ed.w * cv;
        q  += ed.x * gv;
    }
    float* P = PQ2 + node * 80;
    P[f]      = p0;
    P[16 + f] = p1;
    P[32 + f] = p2;
    P[48 + f] = p3;
    P[64 + f] = q;
}

// ---------------------------------------------------------------------------
// K_tf2: per-node transform 2. Thread = (node, o<32), o fixed; 96 weight
// floats in VGPRs; grid-stride (8 nodes/block/iter).
//   c2 = relu(P0@be2 + sum_s Ps@We2_s + c1_self@root2 + bias2)
//   g2 = relu(Q@Wg2 + b_gcn2)
// Output g2c2[n,64] = [g2(32)|c2(32)] (matches concat(p1,p2) order).
// ---------------------------------------------------------------------------
__global__ __launch_bounds__(256, 3) void k_tf2(
    const float* __restrict__ PQ2,
    const float* __restrict__ g1c1,
    const float* __restrict__ Wg2,   // [16,32]
    const float* __restrict__ We2,   // [3,512]
    const float* __restrict__ be2,   // [512]
    const float* __restrict__ root2, // [16,32]
    const float* __restrict__ bias2, // [32]
    const float* __restrict__ bg2,   // [32]
    float* __restrict__ g2c2)
{
    // LDS: wg(512)|w0|w1|w2|bm|rt (512 each) | bias2(32) | bg2(32)
    __shared__ float w[6 * 512 + 64];
    for (int t = threadIdx.x; t < 6 * 512 + 64; t += 256) {
        float v;
        if (t < 3072) {
            int slot = t >> 9, r = t & 511;
            if (slot == 0)      v = Wg2[r];
            else if (slot <= 3) v = We2[(slot - 1) * 512 + r];
            else if (slot == 4) v = be2[r];
            else                v = root2[r];
        } else if (t < 3104) v = bias2[t - 3072];
        else                 v = bg2[t - 3104];
        w[t] = v;
    }
    __syncthreads();
    int o = threadIdx.x & 31;
    int ngrp = threadIdx.x >> 5;         // 0..7
    float wg[16], w0[16], w1[16], w2[16], bm[16], rt[16];
#pragma unroll
    for (int f = 0; f < 16; ++f) {
        wg[f] = w[f * 32 + o];
        w0[f] = w[512 + f * 32 + o];
        w1[f] = w[1024 + f * 32 + o];
        w2[f] = w[1536 + f * 32 + o];
        bm[f] = w[2048 + f * 32 + o];
        rt[f] = w[2560 + f * 32 + o];
    }
    float bia = w[3072 + o], bgv = w[3104 + o];
    for (int node = blockIdx.x * 8 + ngrp; node < N_NODES; node += gridDim.x * 8) {
        const float* P = PQ2 + node * 80;
        const float* cs = g1c1 + node * 32 + 16;   // c1 self row
        float ac = bia, ag = bgv;
#pragma unroll
        for (int f = 0; f < 16; ++f) {
            ac += P[f] * bm[f] + P[16 + f] * w0[f] + P[32 + f] * w1[f]
                + P[48 + f] * w2[f] + cs[f] * rt[f];
            ag += P[64 + f] * wg[f];
        }
        g2c2[node * 64 + o]      = ag > 0.f ? ag : 0.f;
        g2c2[node * 64 + 32 + o] = ac > 0.f ? ac : 0.f;
    }
}

// ---------------------------------------------------------------------------
// K_pool_head: one block per graph. 4 waves stride nodes (lane = channel),
// LDS-reduce, fused MLP head. No atomics.
// ---------------------------------------------------------------------------
__global__ __launch_bounds__(256) void k_pool_head(
    const float* __restrict__ g2c2,
    const int* __restrict__ gs,
    const float* __restrict__ Wd1, const float* __restrict__ bd1,
    const float* __restrict__ Wd2, const float* __restrict__ bd2,
    const float* __restrict__ Wo,  const float* __restrict__ bo,
    float* __restrict__ out)
{
    __shared__ float red[4][64];
    __shared__ float pl[64];
    __shared__ float h1s[16], h2s[8];
    int g = blockIdx.x;
    int s = gs[g], e = gs[g + 1];
    int wv = threadIdx.x >> 6, j = threadIdx.x & 63;
    float acc = 0.f;
    for (int n = s + wv; n < e; n += 4)
        acc += g2c2[n * 64 + j];
    red[wv][j] = acc;
    __syncthreads();
    if (wv == 0) pl[j] = red[0][j] + red[1][j] + red[2][j] + red[3][j];
    __syncthreads();
    int t = threadIdx.x;
    if (t < 16) {
        float a = bd1[t];
        for (int k = 0; k < 64; ++k) a += pl[k] * Wd1[k * 16 + t];
        h1s[t] = a > 0.f ? a : 0.f;
    }
    __syncthreads();
    if (t < 8) {
        float a = bd2[t];
        for (int k = 0; k < 16; ++k) a += h1s[k] * Wd2[k * 8 + t];
        h2s[t] = a > 0.f ? a : 0.f;
    }
    __syncthreads();
    if (t == 0) {
        float a = bo[0];
        for (int k = 0; k < 8; ++k) a += h2s[k] * Wo[k];
        out[g] = 1.f / (1.f + expf(-a));
    }
}

// ---------------------------------------------------------------------------
// Workspace layout (~60 MB):
//   edata E*float4 | PQ1 N*50 | g1c1 N*32 | PQ2 N*80 | g2c2 N*64 (floats)
//   rs[N] | bsum[256] | gs[G+1] | ecol[E] (ints)
// ---------------------------------------------------------------------------
extern "C" void kernel_launch(void* const* d_in, const int* in_sizes, int n_in,
                              void* d_out, int out_size, void* d_ws, size_t ws_size,
                              hipStream_t stream)
{
    const float* x      = (const float*)d_in[0];
    const float* a_vals = (const float*)d_in[1];
    const float* efeat  = (const float*)d_in[2];
    const int*   ei     = (const int*)d_in[3];
    const int*   seg    = (const int*)d_in[4];
    const float* Wg1    = (const float*)d_in[5];
    const float* bg1    = (const float*)d_in[6];
    const float* Wg2    = (const float*)d_in[7];
    const float* bg2    = (const float*)d_in[8];
    const float* We1    = (const float*)d_in[9];
    const float* be1    = (const float*)d_in[10];
    const float* root1  = (const float*)d_in[11];
    const float* bias1  = (const float*)d_in[12];
    const float* We2    = (const float*)d_in[13];
    const float* be2    = (const float*)d_in[14];
    const float* root2  = (const float*)d_in[15];
    const float* bias2  = (const float*)d_in[16];
    const float* Wd1    = (const float*)d_in[17];
    const float* bd1    = (const float*)d_in[18];
    const float* Wd2    = (const float*)d_in[19];
    const float* bd2    = (const float*)d_in[20];
    const float* Wo     = (const float*)d_in[21];
    const float* bo     = (const float*)d_in[22];

    float4* edata = (float4*)d_ws;
    float*  PQ1  = (float*)(edata + N_EDGES);
    float*  g1c1 = PQ1 + (size_t)N_NODES * 50;
    float*  PQ2  = g1c1 + (size_t)N_NODES * 32;
    float*  g2c2 = PQ2 + (size_t)N_NODES * 80;
    int*    rs   = (int*)(g2c2 + (size_t)N_NODES * 64);
    int*    bsum = rs + N_NODES;
    int*    gs   = bsum + 256;
    int*    ecol = gs + (G_DIM + 1);
    float*  out  = (float*)d_out;

    hipMemsetAsync(rs, 0, sizeof(int) * N_NODES, stream);

    // CSR build
    k_deg    <<<NB_EDGE, 256, 0, stream>>>(ei, rs);
    k_scan_a <<<NB_SCAN, 256, 0, stream>>>(rs, bsum);
    k_scan_b <<<1, 256, 0, stream>>>(bsum);
    k_fill   <<<NB_EDGE, 256, 0, stream>>>(ei, a_vals, efeat, rs, bsum, ecol, edata);
    k_gseg   <<<NB_SCAN, 256, 0, stream>>>(seg, gs);

    // Layer 1: weight-free edge reduction + node transform
    k_edge1<<<N_NODES * 16 / 256, 256, 0, stream>>>(x, rs, bsum, ecol, edata, PQ1);
    k_tf1  <<<1280, 256, 0, stream>>>(PQ1, x, Wg1, We1, be1, root1, bias1, bg1, g1c1);

    // Layer 2
    k_edge2<<<N_NODES * 16 / 256, 256, 0, stream>>>(g1c1, rs, bsum, ecol, edata, PQ2);
    k_tf2  <<<1280, 256, 0, stream>>>(PQ2, g1c1, Wg2, We2, be2, root2, bias2, bg2, g2c2);

    // Pool + MLP head
    k_pool_head<<<G_DIM, 256, 0, stream>>>(g2c2, gs, Wd1, bd1, Wd2, bd2, Wo, bo, out);
}